// Round 2
// baseline (307.425 us; speedup 1.0000x reference)
//
#include <hip/hip_runtime.h>
#include <math.h>

#define TOK_TOTAL 16384
#define D_MODEL   2048
#define NEXP      64
#define NBLK      256          // 64 tokens per block
#define TAU       1e-3f       // fp32 gap screening threshold (fp32 dot err <= ~1e-4 worst)

#define IDX_OFF   (TOK_TOTAL * NEXP)           // 1048576 floats
#define LOSS_OFF  (IDX_OFF + TOK_TOTAL * 2)    // 1081344

// ws layout (floats)
#define WS_G      0                             // [16384] float4 (i0, i1, g0, g1)
#define WS_FLAGS  (TOK_TOTAL * 4)               // [16384] float 0/1
#define WS_CNT    (WS_FLAGS + TOK_TOTAL)        // [256][64] count partials

// ---------------- K1: fp32 GEMM (lane=token, wave-uniform W) + top-3 + flags ----------------
__global__ __launch_bounds__(256, 1)
void router_gemm(const float* __restrict__ x, const float* __restrict__ W,
                 float* __restrict__ out, float* __restrict__ G,
                 float* __restrict__ flags)
{
    __shared__ float L[NEXP][66];   // transposed logits: L[expert][token], conflict-free
    const int t = threadIdx.x;
    const int q = __builtin_amdgcn_readfirstlane(t >> 6);  // wave id 0..3 (uniform)
    const int l = t & 63;                                   // lane = token-in-block
    const long tok = (long)blockIdx.x * 64 + l;
    const float* __restrict__ xrow = x + tok * D_MODEL;
    const float* __restrict__ Wq   = W + (long)(q * 16) * D_MODEL;

    float acc[16];
    #pragma unroll
    for (int j = 0; j < 16; ++j) acc[j] = 0.f;

    for (int k = 0; k < D_MODEL; k += 4) {
        float4 xv = *(const float4*)(xrow + k);     // per-lane, streams via L1
        #pragma unroll
        for (int j = 0; j < 16; ++j) {
            float4 wv = *(const float4*)(Wq + j * D_MODEL + k);  // wave-uniform -> s_load/broadcast
            acc[j] = fmaf(xv.x, wv.x, acc[j]);
            acc[j] = fmaf(xv.y, wv.y, acc[j]);
            acc[j] = fmaf(xv.z, wv.z, acc[j]);
            acc[j] = fmaf(xv.w, wv.w, acc[j]);
        }
    }

    #pragma unroll
    for (int j = 0; j < 16; ++j) L[q * 16 + j][l] = acc[j];   // stride-1 across lanes
    __syncthreads();

    if (t < 64) {   // wave 0: token t
        float best = -1e30f, sec = -1e30f, third = -1e30f;
        int bi = 0, si = 0;
        for (int e = 0; e < NEXP; ++e) {
            float v = L[e][t];                                 // stride-1 across lanes
            if (v > best)       { third = sec; sec = best; si = bi; best = v; bi = e; }
            else if (v > sec)   { third = sec; sec = v; si = e; }
            else if (v > third) { third = v; }
        }
        float ex  = __expf(sec - best);
        float inv = 1.f / (1.f + ex);
        long tk = (long)blockIdx.x * 64 + t;
        out[IDX_OFF + 2 * tk]     = (float)bi;
        out[IDX_OFF + 2 * tk + 1] = (float)si;
        ((float4*)G)[tk] = make_float4((float)bi, (float)si, inv, ex * inv);
        flags[tk] = ((best - sec < TAU) || (sec - third < TAU)) ? 1.f : 0.f;
    }
}

// ---------------- K2: fp64 repair of flagged tokens (rare) ----------------
__global__ __launch_bounds__(256, 1)
void router_repair(const float* __restrict__ x, const float* __restrict__ W,
                   float* __restrict__ out, float* __restrict__ G,
                   const float* __restrict__ flags)
{
    __shared__ double red[4][NEXP];
    const int t = threadIdx.x;
    const int e = t & 63;
    const int part = t >> 6;
    const long tok0 = (long)blockIdx.x * 64;

    for (int tt = 0; tt < 64; ++tt) {
        if (flags[tok0 + tt] == 0.f) continue;      // uniform branch
        const long tok = tok0 + tt;
        const float* xr = x + tok * D_MODEL;
        const float* wr = W + (long)e * D_MODEL;
        const int k0 = part * 512;
        double s = 0.0;
        for (int i = 0; i < 512; i += 4) {
            float4 xv = *(const float4*)(xr + k0 + i);
            float4 wv = *(const float4*)(wr + k0 + i);
            s = fma((double)xv.x, (double)wv.x, s);
            s = fma((double)xv.y, (double)wv.y, s);
            s = fma((double)xv.z, (double)wv.z, s);
            s = fma((double)xv.w, (double)wv.w, s);
        }
        red[part][e] = s;
        __syncthreads();
        if (t == 0) {
            double best = -1e300, sec = -1e300;
            int bi = 0, si = 0;
            for (int ee = 0; ee < NEXP; ++ee) {
                double v = red[0][ee] + red[1][ee] + red[2][ee] + red[3][ee];
                if (v > best)     { sec = best; si = bi; best = v; bi = ee; }
                else if (v > sec) { sec = v; si = ee; }
            }
            double ex  = exp(sec - best);
            double inv = 1.0 / (1.0 + ex);
            out[IDX_OFF + 2 * tok]     = (float)bi;
            out[IDX_OFF + 2 * tok + 1] = (float)si;
            ((float4*)G)[tok] = make_float4((float)bi, (float)si, (float)inv, (float)(ex * inv));
        }
        __syncthreads();
    }
}

// ---------------- K3: dense gates + per-block expert count partials ----------------
__global__ __launch_bounds__(256, 1)
void router_gates(const float* __restrict__ G, float* __restrict__ out,
                  float* __restrict__ cntp)
{
    __shared__ float4 Gl[64];
    const int t = threadIdx.x;
    const long tok0 = (long)blockIdx.x * 64;
    if (t < 64) Gl[t] = ((const float4*)G)[tok0 + t];
    __syncthreads();

    const int trow  = t >> 2;
    const int ebase = (t & 3) * 16;
    float4 g = Gl[trow];
    const int i0 = (int)g.x, i1 = (int)g.y;
    float vals[16];
    #pragma unroll
    for (int j = 0; j < 16; ++j) {
        int e = ebase + j;
        vals[j] = (e == i0) ? g.z : ((e == i1) ? g.w : 0.f);
    }
    float* orow = out + (tok0 + trow) * NEXP + ebase;
    #pragma unroll
    for (int v4 = 0; v4 < 4; ++v4)
        *(float4*)(orow + v4 * 4) =
            make_float4(vals[v4*4], vals[v4*4+1], vals[v4*4+2], vals[v4*4+3]);

    if (t < 64) {
        float c = 0.f;
        for (int tt = 0; tt < 64; ++tt) {
            float4 gg = Gl[tt];
            if ((int)gg.x == t) c += gg.z;
            if ((int)gg.y == t) c += gg.w;
        }
        cntp[blockIdx.x * 64 + t] = c;
    }
}

// ---------------- K4: load-balance loss ----------------
__global__ void router_loss(const float* __restrict__ cntp, float* __restrict__ out)
{
    __shared__ double sc[NEXP];
    const int e = threadIdx.x;   // 64 threads
    double csum = 0.0;
    for (int b = 0; b < NBLK; ++b) csum += (double)cntp[b * NEXP + e];
    sc[e] = csum;
    __syncthreads();
    if (e == 0) {
        double tot = 0.0;
        for (int i = 0; i < NEXP; ++i) tot += sc[i];
        double loss = 0.0;
        for (int i = 0; i < NEXP; ++i) {
            double d = sc[i] / tot * (double)NEXP - 1.0;
            loss += d * d;
        }
        out[LOSS_OFF] = (float)(loss / NEXP);
    }
}

extern "C" void kernel_launch(void* const* d_in, const int* in_sizes, int n_in,
                              void* d_out, int out_size, void* d_ws, size_t ws_size,
                              hipStream_t stream)
{
    const float* x = (const float*)d_in[0];
    const float* W = (const float*)d_in[1];
    float* out = (float*)d_out;
    float* ws  = (float*)d_ws;          // needs 384 KB
    float* G     = ws + WS_G;
    float* flags = ws + WS_FLAGS;
    float* cntp  = ws + WS_CNT;

    router_gemm  <<<NBLK, 256, 0, stream>>>(x, W, out, G, flags);
    router_repair<<<NBLK, 256, 0, stream>>>(x, W, out, G, flags);
    router_gates <<<NBLK, 256, 0, stream>>>(G, out, cntp);
    router_loss  <<<1, NEXP, 0, stream>>>(cntp, out);
}